// Round 4
// baseline (706.319 us; speedup 1.0000x reference)
//
#include <hip/hip_runtime.h>

#define N_NODES  100000
#define N_EDGES  1200000
#define N_GRAPHS 1024

#define BSH    7
#define BNODES 128
#define NBUCK  782
#define BCAP   2048
#define BINB   512
#define CHUNK  ((N_EDGES + BINB - 1) / BINB)
#define ENCB   1563

__device__ __forceinline__ unsigned short f2bf(float f) {
  unsigned u = __float_as_uint(f);
  return (unsigned short)((u + 0x7fffu + ((u >> 16) & 1u)) >> 16);
}
__device__ __forceinline__ float bf2f(unsigned short b) {
  return __uint_as_float(((unsigned)b) << 16);
}

__global__ __launch_bounds__(256) void k_zero(float* __restrict__ gsum,
                                              int* __restrict__ deg,
                                              int* __restrict__ cur) {
  int i = blockIdx.x * 256 + threadIdx.x;
  if (i < N_GRAPHS * 64) gsum[i] = 0.f;
  if (i < N_NODES) deg[i] = 0;
  if (i < NBUCK) cur[i] = 0;
}

__global__ __launch_bounds__(512) void k_bin(const int* __restrict__ ei,
                                             int* __restrict__ deg,
                                             int* __restrict__ cur,
                                             int* __restrict__ binned) {
  __shared__ int h[NBUCK];
  int t = threadIdx.x, blk = blockIdx.x;
  for (int i = t; i < NBUCK; i += 512) h[i] = 0;
  __syncthreads();
  int start = blk * CHUNK, end = min(start + CHUNK, N_EDGES);
  for (int e = start + 4 * t; e < end; e += 4 * 512) {
    int4 d4 = *(const int4*)&ei[N_EDGES + e];
    atomicAdd(&h[d4.x >> BSH], 1); atomicAdd(&deg[d4.x], 1);
    atomicAdd(&h[d4.y >> BSH], 1); atomicAdd(&deg[d4.y], 1);
    atomicAdd(&h[d4.z >> BSH], 1); atomicAdd(&deg[d4.z], 1);
    atomicAdd(&h[d4.w >> BSH], 1); atomicAdd(&deg[d4.w], 1);
  }
  __syncthreads();
  for (int b = t; b < NBUCK; b += 512) {
    int v = h[b];
    if (v) h[b] = atomicAdd(&cur[b], v);
  }
  __syncthreads();
  for (int e = start + 4 * t; e < end; e += 4 * 512) {
    int4 s4 = *(const int4*)&ei[e];
    int4 d4 = *(const int4*)&ei[N_EDGES + e];
    int b, p;
    b = d4.x >> BSH; p = atomicAdd(&h[b], 1);
    if (p < BCAP) binned[b * BCAP + p] = s4.x | ((d4.x & (BNODES - 1)) << 17);
    b = d4.y >> BSH; p = atomicAdd(&h[b], 1);
    if (p < BCAP) binned[b * BCAP + p] = s4.y | ((d4.y & (BNODES - 1)) << 17);
    b = d4.z >> BSH; p = atomicAdd(&h[b], 1);
    if (p < BCAP) binned[b * BCAP + p] = s4.z | ((d4.z & (BNODES - 1)) << 17);
    b = d4.w >> BSH; p = atomicAdd(&h[b], 1);
    if (p < BCAP) binned[b * BCAP + p] = s4.w | ((d4.w & (BNODES - 1)) << 17);
  }
}

__global__ __launch_bounds__(256) void k_enc(
    const float* __restrict__ x,
    const float* __restrict__ Wenc, const float* __restrict__ benc,
    const float* __restrict__ gamma, const float* __restrict__ beta,
    const float* __restrict__ mean,  const float* __restrict__ var,
    const float* __restrict__ Wgcn,  const int* __restrict__ deg,
    unsigned short* __restrict__ hw) {
  int t = threadIdx.x;
  int lane = t & 63, w = t >> 6;
  int wv = blockIdx.x * 4 + w;
  if (wv >= 6250) return;
  float be = benc[lane];
  float sc = gamma[lane] * rsqrtf(var[lane] + 1e-5f);
  float mu = mean[lane], bt = beta[lane];
  float w0 = Wenc[lane], w1 = Wenc[64 + lane], w2 = Wenc[128 + lane], w3 = Wenc[192 + lane];
  float wreg[64];
  #pragma unroll
  for (int k = 0; k < 64; ++k) wreg[k] = Wgcn[k * 64 + lane];
  int n0 = wv * 16;
  for (int i = 0; i < 16; ++i) {
    int n = n0 + i;
    float4 xv = ((const float4*)x)[n];
    float h = fmaf(xv.w, w3, fmaf(xv.z, w2, fmaf(xv.y, w1, fmaf(xv.x, w0, be))));
    h = fmaxf(h, 0.f);
    float hbn = (h - mu) * sc + bt;
    int hb = __float_as_int(hbn);
    float a0 = 0.f, a1 = 0.f, a2 = 0.f, a3 = 0.f;
    #pragma unroll
    for (int k = 0; k < 64; k += 4) {
      a0 = fmaf(__int_as_float(__builtin_amdgcn_readlane(hb, k)),     wreg[k],     a0);
      a1 = fmaf(__int_as_float(__builtin_amdgcn_readlane(hb, k + 1)), wreg[k + 1], a1);
      a2 = fmaf(__int_as_float(__builtin_amdgcn_readlane(hb, k + 2)), wreg[k + 2], a2);
      a3 = fmaf(__int_as_float(__builtin_amdgcn_readlane(hb, k + 3)), wreg[k + 3], a3);
    }
    float dn = rsqrtf((float)deg[n] + 1.f);
    hw[(size_t)n * 64 + lane] = f2bf(((a0 + a1) + (a2 + a3)) * dn);
  }
}

// 256 threads, 32KB LDS, NO min-waves clause: preserve the round-0 register
// regime (VGPR ~100) that gave 63.6% VALUBusy / pipelined gathers. 782 blocks
// ~= 3/CU, all resident in one round (LDS allows 5, VGPR ~5).
__global__ __launch_bounds__(256) void k_agg(
    const int* __restrict__ cur, const int* __restrict__ binned,
    const int* __restrict__ deg, const unsigned short* __restrict__ hw,
    const int* __restrict__ batch, const float* __restrict__ bgcn,
    float* __restrict__ gsum) {
  __shared__ float agg[BNODES][64];
  int t = threadIdx.x, blk = blockIdx.x;
  int lane = t & 63, w = t >> 6;
  int nE = min(cur[blk], BCAP);
  int b0 = blk * BCAP;
  for (int i = t; i < BNODES * 64; i += 256) ((float*)agg)[i] = 0.f;
  __syncthreads();
  for (int c = w * 64; c < nE; c += 256) {
    int m = min(64, nE - c);
    int vv = (lane < m) ? binned[b0 + c + lane] : 0;
    int j = 0;
    for (; j + 4 <= m; j += 4) {
      int r0 = __builtin_amdgcn_readlane(vv, j);
      int r1 = __builtin_amdgcn_readlane(vv, j + 1);
      int r2 = __builtin_amdgcn_readlane(vv, j + 2);
      int r3 = __builtin_amdgcn_readlane(vv, j + 3);
      float q0 = bf2f(hw[((size_t)(unsigned)(r0 & 0x1FFFF) << 6) + lane]);
      float q1 = bf2f(hw[((size_t)(unsigned)(r1 & 0x1FFFF) << 6) + lane]);
      float q2 = bf2f(hw[((size_t)(unsigned)(r2 & 0x1FFFF) << 6) + lane]);
      float q3 = bf2f(hw[((size_t)(unsigned)(r3 & 0x1FFFF) << 6) + lane]);
      atomicAdd(&agg[(unsigned)r0 >> 17][lane], q0);
      atomicAdd(&agg[(unsigned)r1 >> 17][lane], q1);
      atomicAdd(&agg[(unsigned)r2 >> 17][lane], q2);
      atomicAdd(&agg[(unsigned)r3 >> 17][lane], q3);
    }
    for (; j < m; ++j) {
      int r = __builtin_amdgcn_readlane(vv, j);
      float q = bf2f(hw[((size_t)(unsigned)(r & 0x1FFFF) << 6) + lane]);
      atomicAdd(&agg[(unsigned)r >> 17][lane], q);
    }
  }
  __syncthreads();
  int node0 = blk << BSH;
  float bias = bgcn[lane];
  float vs = 0.f;
  int cg = -1;
  for (int k = 0; k < 32; ++k) {               // 4 waves x 32 nodes = 128
    int nl = w * 32 + k;
    int n = node0 + nl;
    if (n >= N_NODES) break;
    float sum = agg[nl][lane] + bf2f(hw[(size_t)n * 64 + lane]);
    float dn = rsqrtf((float)deg[n] + 1.f);
    float o = fmaxf(fmaf(dn, sum, bias), 0.f);
    int g = batch[n];
    if (g == cg) vs += o;
    else {
      if (cg >= 0) atomicAdd(&gsum[cg * 64 + lane], vs);
      vs = o; cg = g;
    }
  }
  if (cg >= 0) atomicAdd(&gsum[cg * 64 + lane], vs);
}

__global__ void k_cls(const float* __restrict__ gsum, const int* __restrict__ batch,
                      const float* __restrict__ W1, const float* __restrict__ b1,
                      const float* __restrict__ W2, const float* __restrict__ b2,
                      float* __restrict__ out) {
  __shared__ float gm[64];
  __shared__ int cntS;
  int j = threadIdx.x;
  int g = blockIdx.x;
  if (j == 0) {
    int lo = 0, hi = N_NODES;
    while (lo < hi) { int mid = (lo + hi) >> 1; if (batch[mid] < g) lo = mid + 1; else hi = mid; }
    int lo2 = lo, hi2 = N_NODES;
    while (lo2 < hi2) { int mid = (lo2 + hi2) >> 1; if (batch[mid] < g + 1) lo2 = mid + 1; else hi2 = mid; }
    cntS = lo2 - lo;
  }
  __syncthreads();
  float denom = fmaxf((float)cntS, 1.0f);
  gm[j] = gsum[g * 64 + j] / denom;
  __syncthreads();
  float hid = b1[j];
  #pragma unroll
  for (int k = 0; k < 64; ++k) hid += gm[k] * W1[k * 64 + j];
  hid = fmaxf(hid, 0.f);
  float o0 = hid * W2[j * 2 + 0];
  float o1 = hid * W2[j * 2 + 1];
  #pragma unroll
  for (int off = 32; off > 0; off >>= 1) {
    o0 += __shfl_down(o0, off);
    o1 += __shfl_down(o1, off);
  }
  if (j == 0) {
    out[g * 2 + 0] = o0 + b2[0];
    out[g * 2 + 1] = o1 + b2[1];
  }
}

extern "C" void kernel_launch(void* const* d_in, const int* in_sizes, int n_in,
                              void* d_out, int out_size, void* d_ws, size_t ws_size,
                              hipStream_t stream) {
  const float* x     = (const float*)d_in[0];
  const int*   ei    = (const int*)d_in[1];
  const int*   batch = (const int*)d_in[2];
  const float* Wenc  = (const float*)d_in[3];
  const float* benc  = (const float*)d_in[4];
  const float* gamma = (const float*)d_in[5];
  const float* beta  = (const float*)d_in[6];
  const float* mean  = (const float*)d_in[7];
  const float* var   = (const float*)d_in[8];
  const float* Wgcn  = (const float*)d_in[9];
  const float* bgcn  = (const float*)d_in[10];
  const float* W1    = (const float*)d_in[11];
  const float* b1    = (const float*)d_in[12];
  const float* W2    = (const float*)d_in[13];
  const float* b2    = (const float*)d_in[14];
  float* out = (float*)d_out;

  char* ws = (char*)d_ws;
  float*          gsum   = (float*)ws;          ws += (size_t)N_GRAPHS * 64 * 4;
  int*            deg    = (int*)ws;            ws += (size_t)N_NODES * 4;
  int*            cur    = (int*)ws;            ws += (size_t)1024 * 4;
  int*            binned = (int*)ws;            ws += (size_t)NBUCK * BCAP * 4;
  unsigned short* hw     = (unsigned short*)ws; ws += (size_t)N_NODES * 64 * 2;

  k_zero<<<391, 256, 0, stream>>>(gsum, deg, cur);
  k_bin<<<BINB, 512, 0, stream>>>(ei, deg, cur, binned);
  k_enc<<<ENCB, 256, 0, stream>>>(x, Wenc, benc, gamma, beta, mean, var, Wgcn, deg, hw);
  k_agg<<<NBUCK, 256, 0, stream>>>(cur, binned, deg, hw, batch, bgcn, gsum);
  k_cls<<<N_GRAPHS, 64, 0, stream>>>(gsum, batch, W1, b1, W2, b2, out);
}

// Round 6
// 191.294 us; speedup vs baseline: 3.6923x; 3.6923x over previous
//
#include <hip/hip_runtime.h>

#define N_NODES  100000
#define N_EDGES  1200000
#define N_GRAPHS 1024

#define BSH    8                     // 256-node dst buckets
#define BNODES 256
#define NBUCK  391                   // ceil(100000/256)
#define BCAP   4096                  // bucket slot cap (mean 3070, sigma ~55)
#define BINB   512                   // bin-role blocks
#define CHUNK  ((N_EDGES + BINB - 1) / BINB)   // 2344, %4==0
#define ENCB   1563                  // ceil(6250 enc-waves / 4)

__device__ __forceinline__ unsigned short f2bf(float f) {
  unsigned u = __float_as_uint(f);
  return (unsigned short)((u + 0x7fffu + ((u >> 16) & 1u)) >> 16);
}
__device__ __forceinline__ float bf2f(unsigned short b) {
  return __uint_as_float(((unsigned)b) << 16);
}

// ---- zero gsum + cur ----
__global__ __launch_bounds__(256) void k_zero(float* __restrict__ gsum,
                                              int* __restrict__ cur) {
  int i = blockIdx.x * 256 + threadIdx.x;      // 256*256 = 65536
  gsum[i] = 0.f;
  if (i < NBUCK) cur[i] = 0;
}

// ---- fused: blocks 0..BINB-1 = single-pass binning (LDS hist -> one global
//      reservation per (block,bucket) -> scatter into BCAP-strided buckets);
//      blocks BINB.. = encoder + BN + h@W_gcn -> hw (bf16, UNSCALED —
//      norm applied per-edge in k_gather, as in the proven baseline). ----
__global__ __launch_bounds__(256) void k_binenc(
    const int* __restrict__ ei, int* __restrict__ cur, int* __restrict__ binned,
    const float* __restrict__ x,
    const float* __restrict__ Wenc, const float* __restrict__ benc,
    const float* __restrict__ gamma, const float* __restrict__ beta,
    const float* __restrict__ mean,  const float* __restrict__ var,
    const float* __restrict__ Wgcn,
    unsigned short* __restrict__ hw) {
  int t = threadIdx.x;
  int lane = t & 63, w = t >> 6;
  if (blockIdx.x < BINB) {
    __shared__ int h[NBUCK];
    int blk = blockIdx.x;
    for (int i = t; i < NBUCK; i += 256) h[i] = 0;
    __syncthreads();
    int start = blk * CHUNK, end = min(start + CHUNK, N_EDGES);
    for (int e = start + 4 * t; e < end; e += 4 * 256) {   // dst stream, int4
      int4 d4 = *(const int4*)&ei[N_EDGES + e];
      atomicAdd(&h[d4.x >> BSH], 1);
      atomicAdd(&h[d4.y >> BSH], 1);
      atomicAdd(&h[d4.z >> BSH], 1);
      atomicAdd(&h[d4.w >> BSH], 1);
    }
    __syncthreads();
    for (int b = t; b < NBUCK; b += 256) {     // one reservation per bucket
      int v = h[b];
      if (v) h[b] = atomicAdd(&cur[b], v);
    }
    __syncthreads();
    for (int e = start + 4 * t; e < end; e += 4 * 256) {   // scatter
      int4 s4 = *(const int4*)&ei[e];
      int4 d4 = *(const int4*)&ei[N_EDGES + e];            // L2-hot re-read
      int b, p;
      b = d4.x >> BSH; p = atomicAdd(&h[b], 1);
      if (p < BCAP) binned[b * BCAP + p] = s4.x | ((d4.x & (BNODES - 1)) << 17);
      b = d4.y >> BSH; p = atomicAdd(&h[b], 1);
      if (p < BCAP) binned[b * BCAP + p] = s4.y | ((d4.y & (BNODES - 1)) << 17);
      b = d4.z >> BSH; p = atomicAdd(&h[b], 1);
      if (p < BCAP) binned[b * BCAP + p] = s4.z | ((d4.z & (BNODES - 1)) << 17);
      b = d4.w >> BSH; p = atomicAdd(&h[b], 1);
      if (p < BCAP) binned[b * BCAP + p] = s4.w | ((d4.w & (BNODES - 1)) << 17);
    }
    return;
  }
  // ------- encoder role -------
  int wv = (blockIdx.x - BINB) * 4 + w;            // 16 nodes per wave
  if (wv >= 6250) return;
  float be = benc[lane];
  float sc = gamma[lane] * rsqrtf(var[lane] + 1e-5f);
  float mu = mean[lane], bt = beta[lane];
  float w0 = Wenc[lane], w1 = Wenc[64 + lane], w2 = Wenc[128 + lane], w3 = Wenc[192 + lane];
  float wreg[64];
  #pragma unroll
  for (int k = 0; k < 64; ++k) wreg[k] = Wgcn[k * 64 + lane];   // W column j=lane
  int n0 = wv * 16;
  for (int i = 0; i < 16; ++i) {
    int n = n0 + i;                                  // 6250*16 = 100000 exact
    float4 xv = ((const float4*)x)[n];               // wave-uniform broadcast
    float h = fmaf(xv.w, w3, fmaf(xv.z, w2, fmaf(xv.y, w1, fmaf(xv.x, w0, be))));
    h = fmaxf(h, 0.f);                               // ReLU (dropout = identity)
    float hbn = (h - mu) * sc + bt;                  // BatchNorm (running stats)
    int hb = __float_as_int(hbn);
    float a0 = 0.f, a1 = 0.f, a2 = 0.f, a3 = 0.f;
    #pragma unroll
    for (int k = 0; k < 64; k += 4) {
      a0 = fmaf(__int_as_float(__builtin_amdgcn_readlane(hb, k)),     wreg[k],     a0);
      a1 = fmaf(__int_as_float(__builtin_amdgcn_readlane(hb, k + 1)), wreg[k + 1], a1);
      a2 = fmaf(__int_as_float(__builtin_amdgcn_readlane(hb, k + 2)), wreg[k + 2], a2);
      a3 = fmaf(__int_as_float(__builtin_amdgcn_readlane(hb, k + 3)), wreg[k + 3], a3);
    }
    hw[(size_t)n * 64 + lane] = f2bf((a0 + a1) + (a2 + a3));
  }
}

// ---- per-bucket: LDS hist + scan -> packed rowinfo / dis, sort into csr ----
__global__ __launch_bounds__(256) void k_csr(const int* __restrict__ cur,
                                             const int* __restrict__ binned,
                                             int* __restrict__ csr,
                                             unsigned* __restrict__ rowinfo,
                                             float* __restrict__ dis) {
  __shared__ int hist[BNODES];
  __shared__ int wsum[4];
  int t = threadIdx.x, blk = blockIdx.x;
  int lane = t & 63, w = t >> 6;
  int nE = min(cur[blk], BCAP);
  int b0 = blk * BCAP;
  hist[t] = 0;
  __syncthreads();
  for (int i = t; i < nE; i += 256)
    atomicAdd(&hist[(unsigned)binned[b0 + i] >> 17], 1);
  __syncthreads();
  int v = hist[t];                       // full in-degree (buckets partition dst)
  int incl = v;
  #pragma unroll
  for (int off = 1; off < 64; off <<= 1) {
    int y = __shfl_up(incl, off);
    if (lane >= off) incl += y;
  }
  if (lane == 63) wsum[w] = incl;
  __syncthreads();
  if (t == 0) {
    int s = 0;
    #pragma unroll
    for (int i = 0; i < 4; ++i) { int x2 = wsum[i]; wsum[i] = s; s += x2; }
  }
  __syncthreads();
  int excl = wsum[w] + incl - v;
  hist[t] = excl;                        // reuse as scatter cursor
  int node = (blk << BSH) + t;
  if (node < N_NODES) {
    rowinfo[node] = (unsigned)(b0 + excl) | ((unsigned)v << 21);  // st<2^21, v<2^11
    dis[node] = rsqrtf((float)(v + 1));  // +1 self-loop
  }
  __syncthreads();
  for (int i = t; i < nE; i += 256) {
    int vv = binned[b0 + i];
    int p = atomicAdd(&hist[(unsigned)vv >> 17], 1);
    csr[b0 + p] = vv & 0x1FFFF;
  }
}

// ---- CSR gather (proven baseline structure): 64-thr blocks, 4 nodes each;
//      per-chunk vector gather of dis, per-edge readlane broadcasts ----
__global__ __launch_bounds__(64) void k_gather(
    const unsigned* __restrict__ rowinfo, const int* __restrict__ csr,
    const float* __restrict__ dis, const unsigned short* __restrict__ hw,
    const int* __restrict__ batch, const float* __restrict__ bgcn,
    float* __restrict__ gsum) {
  int lane = threadIdx.x;              // one wave per block
  int nb = blockIdx.x * 4;             // 25000 blocks, no tail
  float bias = bgcn[lane];
  float vout[4];
  int gid[4];
  #pragma unroll
  for (int k = 0; k < 4; ++k) {
    int n = nb + k;                    // uniform: blockIdx-derived only
    unsigned u = rowinfo[n];
    int st = (int)(u & 0x1FFFFF);
    int v  = (int)(u >> 21);
    int en = st + v;
    float dn = rsqrtf((float)(v + 1));
    float a0 = 0.f, a1 = 0.f, a2 = 0.f, a3 = 0.f;
    for (int c = st; c < en; c += 64) {
      int m = min(64, en - c);         // uniform
      int idx = c + lane;
      int chunk = 0; float dv = 0.f;
      if (idx < en) { chunk = csr[idx]; dv = dis[chunk]; }   // vector gather
      int dvb = __float_as_int(dv);
      int j = 0;
      for (; j + 4 <= m; j += 4) {     // j uniform -> SGPR readlane
        int s0 = __builtin_amdgcn_readlane(chunk, j);
        int s1 = __builtin_amdgcn_readlane(chunk, j + 1);
        int s2 = __builtin_amdgcn_readlane(chunk, j + 2);
        int s3 = __builtin_amdgcn_readlane(chunk, j + 3);
        float d0 = __int_as_float(__builtin_amdgcn_readlane(dvb, j));
        float d1 = __int_as_float(__builtin_amdgcn_readlane(dvb, j + 1));
        float d2 = __int_as_float(__builtin_amdgcn_readlane(dvb, j + 2));
        float d3 = __int_as_float(__builtin_amdgcn_readlane(dvb, j + 3));
        a0 = fmaf(d0, bf2f(hw[(size_t)s0 * 64 + lane]), a0);
        a1 = fmaf(d1, bf2f(hw[(size_t)s1 * 64 + lane]), a1);
        a2 = fmaf(d2, bf2f(hw[(size_t)s2 * 64 + lane]), a2);
        a3 = fmaf(d3, bf2f(hw[(size_t)s3 * 64 + lane]), a3);
      }
      for (; j < m; ++j) {
        int s = __builtin_amdgcn_readlane(chunk, j);
        float d = __int_as_float(__builtin_amdgcn_readlane(dvb, j));
        a0 = fmaf(d, bf2f(hw[(size_t)s * 64 + lane]), a0);
      }
    }
    float self = bf2f(hw[(size_t)n * 64 + lane]);
    float sum = (a0 + a1) + (a2 + a3);
    vout[k] = fmaxf(dn * fmaf(dn, self, sum) + bias, 0.f);   // dn*(sum + dn*self) + b
    gid[k] = batch[n];
  }
  float vs = vout[0];
  int cg = gid[0];
  #pragma unroll
  for (int k = 1; k < 4; ++k) {
    if (gid[k] == cg) vs += vout[k];
    else {
      atomicAdd(&gsum[cg * 64 + lane], vs);
      vs = vout[k]; cg = gid[k];
    }
  }
  atomicAdd(&gsum[cg * 64 + lane], vs);
}

// ---- classifier; graph count via binary search on sorted batch ----
__global__ void k_cls(const float* __restrict__ gsum, const int* __restrict__ batch,
                      const float* __restrict__ W1, const float* __restrict__ b1,
                      const float* __restrict__ W2, const float* __restrict__ b2,
                      float* __restrict__ out) {
  __shared__ float gm[64];
  __shared__ int cntS;
  int j = threadIdx.x;
  int g = blockIdx.x;
  if (j == 0) {
    int lo = 0, hi = N_NODES;
    while (lo < hi) { int mid = (lo + hi) >> 1; if (batch[mid] < g) lo = mid + 1; else hi = mid; }
    int lo2 = lo, hi2 = N_NODES;
    while (lo2 < hi2) { int mid = (lo2 + hi2) >> 1; if (batch[mid] < g + 1) lo2 = mid + 1; else hi2 = mid; }
    cntS = lo2 - lo;
  }
  __syncthreads();
  float denom = fmaxf((float)cntS, 1.0f);
  gm[j] = gsum[g * 64 + j] / denom;
  __syncthreads();
  float hid = b1[j];
  #pragma unroll
  for (int k = 0; k < 64; ++k) hid += gm[k] * W1[k * 64 + j];
  hid = fmaxf(hid, 0.f);
  float o0 = hid * W2[j * 2 + 0];
  float o1 = hid * W2[j * 2 + 1];
  #pragma unroll
  for (int off = 32; off > 0; off >>= 1) {
    o0 += __shfl_down(o0, off);
    o1 += __shfl_down(o1, off);
  }
  if (j == 0) {
    out[g * 2 + 0] = o0 + b2[0];
    out[g * 2 + 1] = o1 + b2[1];
  }
}

extern "C" void kernel_launch(void* const* d_in, const int* in_sizes, int n_in,
                              void* d_out, int out_size, void* d_ws, size_t ws_size,
                              hipStream_t stream) {
  const float* x     = (const float*)d_in[0];
  const int*   ei    = (const int*)d_in[1];
  const int*   batch = (const int*)d_in[2];
  const float* Wenc  = (const float*)d_in[3];
  const float* benc  = (const float*)d_in[4];
  const float* gamma = (const float*)d_in[5];
  const float* beta  = (const float*)d_in[6];
  const float* mean  = (const float*)d_in[7];
  const float* var   = (const float*)d_in[8];
  const float* Wgcn  = (const float*)d_in[9];
  const float* bgcn  = (const float*)d_in[10];
  const float* W1    = (const float*)d_in[11];
  const float* b1    = (const float*)d_in[12];
  const float* W2    = (const float*)d_in[13];
  const float* b2    = (const float*)d_in[14];
  float* out = (float*)d_out;

  char* ws = (char*)d_ws;
  float*          gsum    = (float*)ws;          ws += (size_t)N_GRAPHS * 64 * 4;
  int*            cur     = (int*)ws;            ws += (size_t)1024 * 4;
  int*            binned  = (int*)ws;            ws += (size_t)NBUCK * BCAP * 4;
  int*            csr     = (int*)ws;            ws += (size_t)NBUCK * BCAP * 4;
  unsigned*       rowinfo = (unsigned*)ws;       ws += (size_t)(N_NODES + 32) * 4;
  float*          dis     = (float*)ws;          ws += (size_t)N_NODES * 4;
  unsigned short* hw      = (unsigned short*)ws; ws += (size_t)N_NODES * 64 * 2;

  k_zero<<<256, 256, 0, stream>>>(gsum, cur);
  k_binenc<<<BINB + ENCB, 256, 0, stream>>>(ei, cur, binned, x, Wenc, benc,
                                            gamma, beta, mean, var, Wgcn, hw);
  k_csr<<<NBUCK, 256, 0, stream>>>(cur, binned, csr, rowinfo, dis);
  k_gather<<<(N_NODES / 4), 64, 0, stream>>>(rowinfo, csr, dis, hw, batch, bgcn, gsum);
  k_cls<<<N_GRAPHS, 64, 0, stream>>>(gsum, batch, W1, b1, W2, b2, out);
}